// Round 2
// baseline (1206.117 us; speedup 1.0000x reference)
//
#include <hip/hip_runtime.h>
#include <float.h>

#define BQ 8
#define CHN 96
#define NP 3136
#define KNN 9
#define C2 192
#define NCHUNK 7

// ---------- K1: h[b][o][n] = sum_c fc1_w[o][c] * x[b][c][n] + fc1_b[o]
__global__ __launch_bounds__(256) void k1_conv1(const float* __restrict__ x,
    const float* __restrict__ w, const float* __restrict__ bias, float* __restrict__ h) {
  __shared__ float sw[CHN * CHN];   // 36 KB
  __shared__ float sx[CHN][64];     // 24 KB
  int b = blockIdx.y;
  int n0 = blockIdx.x * 64;
  int tid = threadIdx.x;
  for (int i = tid; i < CHN * CHN; i += 256) sw[i] = w[i];
  const float* xb = x + (size_t)b * CHN * NP + n0;
  for (int i = tid; i < CHN * 64; i += 256) {
    int c = i >> 6, nn = i & 63;
    sx[c][nn] = xb[(size_t)c * NP + nn];
  }
  __syncthreads();
  int nn = tid & 63;
  int o0 = (tid >> 6) * 24;          // each wave owns 24 consecutive output channels
  float acc[24];
#pragma unroll
  for (int j = 0; j < 24; ++j) acc[j] = 0.f;
  for (int c = 0; c < CHN; ++c) {
    float xv = sx[c][nn];
#pragma unroll
    for (int j = 0; j < 24; ++j) acc[j] = fmaf(sw[(o0 + j) * CHN + c], xv, acc[j]);
  }
  float* hb = h + (size_t)b * CHN * NP + n0;
#pragma unroll
  for (int j = 0; j < 24; ++j) hb[(size_t)(o0 + j) * NP + nn] = acc[j] + bias[o0 + j];
}

// ---------- K2/K7: per-(b,channel) mean + rstd over NP spatial positions
__global__ __launch_bounds__(256) void k2_stats(const float* __restrict__ src,
                                                float* __restrict__ stat) {
  int bo = blockIdx.x;
  const float* p = src + (size_t)bo * NP;
  float s = 0.f, ss = 0.f;
  for (int i = threadIdx.x; i < NP; i += 256) { float v = p[i]; s += v; ss = fmaf(v, v, ss); }
#pragma unroll
  for (int off = 32; off; off >>= 1) { s += __shfl_down(s, off); ss += __shfl_down(ss, off); }
  __shared__ float as[4], ass[4];
  int wv = threadIdx.x >> 6;
  if ((threadIdx.x & 63) == 0) { as[wv] = s; ass[wv] = ss; }
  __syncthreads();
  if (threadIdx.x == 0) {
    float S = as[0] + as[1] + as[2] + as[3];
    float SS = ass[0] + ass[1] + ass[2] + ass[3];
    float mean = S * (1.f / NP);
    float var = SS * (1.f / NP) - mean * mean;
    if (var < 0.f) var = 0.f;
    stat[bo * 2] = mean;
    stat[bo * 2 + 1] = 1.f / sqrtf(var + 1e-5f);
  }
}

// ---------- K3: normalize h -> feats[b][n][c]; nrm = feats/max(||f||,eps); sq = sum(nrm^2)
__global__ __launch_bounds__(256) void k3_norm(const float* __restrict__ h,
    const float* __restrict__ stat, float* __restrict__ feats, float* __restrict__ nrm,
    float* __restrict__ sq) {
  __shared__ float tile[CHN][33];
  __shared__ float part[8][32];
  __shared__ float sinv[32];
  int b = blockIdx.y, n0 = blockIdx.x * 32;
  int tid = threadIdx.x;
  for (int i = tid; i < CHN * 32; i += 256) {
    int c = i >> 5, nn = i & 31;
    float m = stat[(b * CHN + c) * 2];
    float r = stat[(b * CHN + c) * 2 + 1];
    tile[c][nn] = (h[((size_t)(b * CHN + c)) * NP + n0 + nn] - m) * r;
  }
  __syncthreads();
  int nn = tid & 31, sub = tid >> 5;
  float ss = 0.f;
#pragma unroll
  for (int j = 0; j < 12; ++j) { float f = tile[sub * 12 + j][nn]; ss = fmaf(f, f, ss); }
  part[sub][nn] = ss;
  __syncthreads();
  if (tid < 32) {
    float S = 0.f;
#pragma unroll
    for (int w = 0; w < 8; ++w) S += part[w][tid];
    float norm = sqrtf(S);
    sinv[tid] = 1.f / fmaxf(norm, 1e-12f);
  }
  __syncthreads();
  float inv = sinv[nn];
  float ss2 = 0.f;
#pragma unroll
  for (int j = 0; j < 12; ++j) { float f = tile[sub * 12 + j][nn] * inv; ss2 = fmaf(f, f, ss2); }
  part[sub][nn] = ss2;
  __syncthreads();
  if (tid < 32) {
    float S = 0.f;
#pragma unroll
    for (int w = 0; w < 8; ++w) S += part[w][tid];
    sq[(size_t)b * NP + n0 + tid] = S;
  }
  for (int i = tid; i < 32 * CHN; i += 256) {
    int nn2 = i / CHN, c = i - nn2 * CHN;
    float f = tile[c][nn2];
    size_t o = ((size_t)b * NP + n0 + nn2) * CHN + c;
    feats[o] = f;
    nrm[o] = f * sinv[nn2];
  }
}

// ---------- K4: fused pairwise distance + per-row top-9 (per m-chunk), stable tie-break
// __launch_bounds__(256, 1): allow up to 512 VGPR so float4 r[24] (96 VGPRs)
// stays register-resident. Round-1 run showed VGPR_Count=92 -> r[] spilled to
// scratch -> 56 GB HBM FETCH per dispatch, 975 us.
__global__ __launch_bounds__(256, 1) void k4_topk(const float* __restrict__ nrm,
    const float* __restrict__ sq, float* __restrict__ pd, int* __restrict__ pi) {
  int b = blockIdx.z, chunk = blockIdx.y;
  int n = blockIdx.x * 256 + threadIdx.x;
  int nc = n < NP ? n : NP - 1;
  const float* nb = nrm + (size_t)b * NP * CHN;
  float4 r[24];
  const float4* rp = (const float4*)(nb + (size_t)nc * CHN);
#pragma unroll
  for (int i = 0; i < 24; ++i) r[i] = rp[i];
  float sqn = sq[(size_t)b * NP + nc];
  float tv[KNN]; int ti[KNN];
#pragma unroll
  for (int i = 0; i < KNN; ++i) { tv[i] = FLT_MAX; ti[i] = 0x7fffffff; }
  __shared__ float sm[64 * CHN];   // 24 KB m-tile
  __shared__ float ssq[64];
  const int CSZ = NP / NCHUNK;     // 448
  int m0b = chunk * CSZ;
  for (int t = 0; t < CSZ / 64; ++t) {
    int m0 = m0b + t * 64;
    __syncthreads();
    for (int i = threadIdx.x; i < 64 * CHN; i += 256) sm[i] = nb[(size_t)m0 * CHN + i];
    if (threadIdx.x < 64) ssq[threadIdx.x] = sq[(size_t)b * NP + m0 + threadIdx.x];
    __syncthreads();
    for (int mm = 0; mm < 64; ++mm) {
      const float4* mp = (const float4*)(sm + mm * CHN);
      float ax = 0.f, ay = 0.f, az = 0.f, aw = 0.f;
#pragma unroll
      for (int i = 0; i < 24; ++i) {
        float4 mv = mp[i];
        ax = fmaf(r[i].x, mv.x, ax); ay = fmaf(r[i].y, mv.y, ay);
        az = fmaf(r[i].z, mv.z, az); aw = fmaf(r[i].w, mv.w, aw);
      }
      float dot = (ax + ay) + (az + aw);
      float d = sqn + ssq[mm] - 2.f * dot;
      int m = m0 + mm;
      if (d < tv[KNN - 1]) {        // strict <: equal dist keeps earlier index (lax.top_k)
        tv[8] = d; ti[8] = m;
#pragma unroll
        for (int j = 8; j > 0; --j) {
          bool swp = tv[j] < tv[j - 1];
          float fa = swp ? tv[j] : tv[j - 1];
          float fb = swp ? tv[j - 1] : tv[j];
          int ia = swp ? ti[j] : ti[j - 1];
          int ib = swp ? ti[j - 1] : ti[j];
          tv[j - 1] = fa; tv[j] = fb; ti[j - 1] = ia; ti[j] = ib;
        }
      }
    }
  }
  if (n < NP) {
    size_t base = (((size_t)b * NCHUNK + chunk) * NP + n) * (size_t)KNN;
#pragma unroll
    for (int i = 0; i < KNN; ++i) { pd[base + i] = tv[i]; pi[base + i] = ti[i]; }
  }
}

// ---------- K4b: merge NCHUNK sorted top-9 lists per row (lexicographic selection)
__global__ __launch_bounds__(64) void k4b_merge(const float* __restrict__ pd,
    const int* __restrict__ pi, int* __restrict__ nidx) {
  int gid = blockIdx.x * 64 + threadIdx.x;
  int b = gid / NP, n = gid - b * NP;
  float cd[NCHUNK * KNN]; int ci[NCHUNK * KNN];
#pragma unroll
  for (int ch = 0; ch < NCHUNK; ++ch) {
    size_t base = (((size_t)b * NCHUNK + ch) * NP + n) * (size_t)KNN;
#pragma unroll
    for (int k = 0; k < KNN; ++k) {
      cd[ch * KNN + k] = pd[base + k];
      ci[ch * KNN + k] = pi[base + k];
    }
  }
  float dl = -FLT_MAX; int il = -1;
  int* op = nidx + (size_t)gid * KNN;
  for (int k = 0; k < KNN; ++k) {
    float bd = FLT_MAX; int bi = 0x7fffffff;
#pragma unroll
    for (int j = 0; j < NCHUNK * KNN; ++j) {
      bool gt = (cd[j] > dl) || ((cd[j] == dl) && (ci[j] > il));
      bool lt = (cd[j] < bd) || ((cd[j] == bd) && (ci[j] < bi));
      if (gt && lt) { bd = cd[j]; bi = ci[j]; }
    }
    op[k] = bi;
    dl = bd; il = bi;
  }
}

// ---------- K5: a[b][n][o] = (W1-W2)·f + gb ; u[b][n][o] = W2·f   (o < 192)
__global__ __launch_bounds__(256) void k5_au(const float* __restrict__ feats,
    const float* __restrict__ gw, const float* __restrict__ gb,
    float* __restrict__ a, float* __restrict__ u) {
  __shared__ float sf[32][97];       // 12.4 KB, padded
  __shared__ float swc[64 * C2];     // 48 KB: 64 gconv rows (both halves)
  int b = blockIdx.y, n0 = blockIdx.x * 32;
  int tid = threadIdx.x;
  for (int i = tid; i < 32 * CHN; i += 256) {
    int nn = i / CHN, c = i - nn * CHN;
    sf[nn][c] = feats[((size_t)b * NP + n0 + nn) * CHN + c];
  }
  int nn = tid & 31, sub = tid >> 5;
  for (int oc = 0; oc < 3; ++oc) {
    __syncthreads();
    for (int i = tid; i < 64 * C2; i += 256) swc[i] = gw[(size_t)(oc * 64) * C2 + i];
    __syncthreads();
    float accA[8], accU[8];
#pragma unroll
    for (int j = 0; j < 8; ++j) { accA[j] = 0.f; accU[j] = 0.f; }
    for (int c = 0; c < CHN; ++c) {
      float f = sf[nn][c];
#pragma unroll
      for (int j = 0; j < 8; ++j) {
        float w1 = swc[(sub * 8 + j) * C2 + c];
        float wv2 = swc[(sub * 8 + j) * C2 + 96 + c];
        accA[j] = fmaf(w1 - wv2, f, accA[j]);
        accU[j] = fmaf(wv2, f, accU[j]);
      }
    }
    size_t row = ((size_t)b * NP + n0 + nn) * C2;
#pragma unroll
    for (int j = 0; j < 8; ++j) {
      int o = oc * 64 + sub * 8 + j;
      a[row + o] = accA[j] + gb[o];
      u[row + o] = accU[j];
    }
  }
}

// ---------- K6: agg = relu(a + max_k u[idx_k])  then  ol[b][o2][n] = fc2_w·agg + fc2_b
__global__ __launch_bounds__(256) void k6_edge(const float* __restrict__ a,
    const float* __restrict__ u, const int* __restrict__ nidx,
    const float* __restrict__ w2, const float* __restrict__ b2, float* __restrict__ ol) {
  __shared__ float sagg[32][193];    // 24.7 KB, padded
  int b = blockIdx.y, n0 = blockIdx.x * 32;
  int tid = threadIdx.x;
  int wv = tid >> 6, ln = tid & 63;
  for (int p = 0; p < 8; ++p) {
    int nn = wv * 8 + p;
    size_t row = (size_t)b * NP + n0 + nn;
    const int* ip = nidx + row * KNN;
    int idx[KNN];
#pragma unroll
    for (int k = 0; k < KNN; ++k) idx[k] = ip[k];
#pragma unroll
    for (int oo = 0; oo < 3; ++oo) {
      int o = oo * 64 + ln;
      float umax = -FLT_MAX;
#pragma unroll
      for (int k = 0; k < KNN; ++k)
        umax = fmaxf(umax, u[((size_t)b * NP + idx[k]) * C2 + o]);
      float av = a[row * C2 + o];
      sagg[nn][o] = fmaxf(av + umax, 0.f);   // max_k relu(a+u_k) == relu(a + max_k u_k)
    }
  }
  __syncthreads();
  int nn = tid & 31, sub = tid >> 5;
  for (int j = 0; j < 12; ++j) {
    int o2 = sub + 8 * j;
    float acc = b2[o2];
    for (int o = 0; o < C2; ++o) acc = fmaf(w2[o2 * C2 + o], sagg[nn][o], acc);
    ol[((size_t)b * CHN + o2) * NP + n0 + nn] = acc;
  }
}

// ---------- K8: out = (ol - mean)*rstd + shortcut
__global__ __launch_bounds__(256) void k8_final(const float* __restrict__ ol,
    const float* __restrict__ stat, const float* __restrict__ x, float* __restrict__ out) {
  int i = blockIdx.x * 256 + threadIdx.x;
  int bo = i / NP;
  float m = stat[bo * 2], r = stat[bo * 2 + 1];
  out[i] = fmaf(ol[i] - m, r, x[i]);
}

extern "C" void kernel_launch(void* const* d_in, const int* in_sizes, int n_in,
                              void* d_out, int out_size, void* d_ws, size_t ws_size,
                              hipStream_t stream) {
  const float* x   = (const float*)d_in[0];
  const float* f1w = (const float*)d_in[1];
  const float* f1b = (const float*)d_in[2];
  const float* gw  = (const float*)d_in[3];
  const float* gb  = (const float*)d_in[4];
  const float* f2w = (const float*)d_in[5];
  const float* f2b = (const float*)d_in[6];
  float* out = (float*)d_out;
  char* ws = (char*)d_ws;

  constexpr size_t SZ_MAT  = (size_t)BQ * CHN * NP * 4;            // 9,633,792 B
  constexpr size_t OFF_H   = 0;
  constexpr size_t OFF_FE  = OFF_H + SZ_MAT;
  constexpr size_t OFF_NRM = OFF_FE + SZ_MAT;                      // reused as ol after K4
  constexpr size_t OFF_SQ  = OFF_NRM + SZ_MAT;
  constexpr size_t OFF_ST1 = OFF_SQ + (size_t)BQ * NP * 4;
  constexpr size_t OFF_ST2 = OFF_ST1 + (size_t)BQ * CHN * 2 * 4;
  constexpr size_t OFF_NI  = OFF_ST2 + (size_t)BQ * CHN * 2 * 4;
  constexpr size_t OFF_PD  = OFF_NI + (size_t)BQ * NP * KNN * 4;
  constexpr size_t OFF_PI  = OFF_PD + (size_t)BQ * NCHUNK * NP * KNN * 4;
  constexpr size_t OFF_A   = OFF_PD;                               // alias: pd/pi dead after K4b
  constexpr size_t OFF_U   = OFF_PD + (size_t)BQ * NP * C2 * 4;
  // total ws needed: OFF_U + B*N*C2*4 = 68,452,352 B

  float* h   = (float*)(ws + OFF_H);
  float* fe  = (float*)(ws + OFF_FE);
  float* nrm = (float*)(ws + OFF_NRM);
  float* sq  = (float*)(ws + OFF_SQ);
  float* st1 = (float*)(ws + OFF_ST1);
  float* st2 = (float*)(ws + OFF_ST2);
  int*   ni  = (int*)(ws + OFF_NI);
  float* pd  = (float*)(ws + OFF_PD);
  int*   pi  = (int*)(ws + OFF_PI);
  float* aA  = (float*)(ws + OFF_A);
  float* uU  = (float*)(ws + OFF_U);
  float* ol  = nrm;

  k1_conv1<<<dim3(NP / 64, BQ), 256, 0, stream>>>(x, f1w, f1b, h);
  k2_stats<<<dim3(BQ * CHN), 256, 0, stream>>>(h, st1);
  k3_norm<<<dim3(NP / 32, BQ), 256, 0, stream>>>(h, st1, fe, nrm, sq);
  k4_topk<<<dim3((NP + 255) / 256, NCHUNK, BQ), 256, 0, stream>>>(nrm, sq, pd, pi);
  k4b_merge<<<dim3(BQ * NP / 64), 64, 0, stream>>>(pd, pi, ni);
  k5_au<<<dim3(NP / 32, BQ), 256, 0, stream>>>(fe, gw, gb, aA, uU);
  k6_edge<<<dim3(NP / 32, BQ), 256, 0, stream>>>(aA, uU, ni, f2w, f2b, ol);
  k2_stats<<<dim3(BQ * CHN), 256, 0, stream>>>(ol, st2);
  k8_final<<<dim3(BQ * CHN * NP / 256), 256, 0, stream>>>(ol, st2, x, out);
}

// Round 5
// 1039.942 us; speedup vs baseline: 1.1598x; 1.1598x over previous
//
#include <hip/hip_runtime.h>
#include <float.h>

#define BQ 8
#define CHN 96
#define NP 3136
#define KNN 9
#define C2 192
#define NT 196        // 16-wide tiles along n/m
#define MCH 4         // m-chunks
#define TPC (NT/MCH)  // 49 tiles per chunk
#define NFRAG 9       // 3-way split: h0,h1,h2,m0,m1,m2,l0,l1,l2
#define NLIST 16      // partial top-9 lists per query (4 m-chunks x 4 lane-groups)

typedef __attribute__((ext_vector_type(8))) short bf16x8;
typedef __attribute__((ext_vector_type(4))) float f32x4;

__device__ inline ushort f2bf(float x) {            // round-to-nearest-even
  unsigned u = __float_as_uint(x);
  return (ushort)((u + 0x7FFFu + ((u >> 16) & 1u)) >> 16);
}
__device__ inline float bf2f(ushort h) { return __uint_as_float((unsigned)h << 16); }

__device__ inline void gl2lds16(const void* g, void* l) {
  __builtin_amdgcn_global_load_lds(
      (const __attribute__((address_space(1))) unsigned int*)g,
      (__attribute__((address_space(3))) unsigned int*)l, 16, 0, 0);
}

// ---------- K1: h[b][o][n] = sum_c fc1_w[o][c] * x[b][c][n] + fc1_b[o]
__global__ __launch_bounds__(256) void k1_conv1(const float* __restrict__ x,
    const float* __restrict__ w, const float* __restrict__ bias, float* __restrict__ h) {
  __shared__ float sw[CHN * CHN];
  __shared__ float sx[CHN][64];
  int b = blockIdx.y;
  int n0 = blockIdx.x * 64;
  int tid = threadIdx.x;
  for (int i = tid; i < CHN * CHN; i += 256) sw[i] = w[i];
  const float* xb = x + (size_t)b * CHN * NP + n0;
  for (int i = tid; i < CHN * 64; i += 256) {
    int c = i >> 6, nn = i & 63;
    sx[c][nn] = xb[(size_t)c * NP + nn];
  }
  __syncthreads();
  int nn = tid & 63;
  int o0 = (tid >> 6) * 24;
  float acc[24];
#pragma unroll
  for (int j = 0; j < 24; ++j) acc[j] = 0.f;
  for (int c = 0; c < CHN; ++c) {
    float xv = sx[c][nn];
#pragma unroll
    for (int j = 0; j < 24; ++j) acc[j] = fmaf(sw[(o0 + j) * CHN + c], xv, acc[j]);
  }
  float* hb = h + (size_t)b * CHN * NP + n0;
#pragma unroll
  for (int j = 0; j < 24; ++j) hb[(size_t)(o0 + j) * NP + nn] = acc[j] + bias[o0 + j];
}

// ---------- K2/K7: per-(b,channel) mean + rstd
__global__ __launch_bounds__(256) void k2_stats(const float* __restrict__ src,
                                                float* __restrict__ stat) {
  int bo = blockIdx.x;
  const float* p = src + (size_t)bo * NP;
  float s = 0.f, ss = 0.f;
  for (int i = threadIdx.x; i < NP; i += 256) { float v = p[i]; s += v; ss = fmaf(v, v, ss); }
#pragma unroll
  for (int off = 32; off; off >>= 1) { s += __shfl_down(s, off); ss += __shfl_down(ss, off); }
  __shared__ float as[4], ass[4];
  int wv = threadIdx.x >> 6;
  if ((threadIdx.x & 63) == 0) { as[wv] = s; ass[wv] = ss; }
  __syncthreads();
  if (threadIdx.x == 0) {
    float S = as[0] + as[1] + as[2] + as[3];
    float SS = ass[0] + ass[1] + ass[2] + ass[3];
    float mean = S * (1.f / NP);
    float var = SS * (1.f / NP) - mean * mean;
    if (var < 0.f) var = 0.f;
    stat[bo * 2] = mean;
    stat[bo * 2 + 1] = 1.f / sqrtf(var + 1e-5f);
  }
}

// ---------- K3: normalize h -> feats[b][n][c]; nrm = feats/max(||f||,eps); sq = sum(nrm^2)
__global__ __launch_bounds__(256) void k3_norm(const float* __restrict__ h,
    const float* __restrict__ stat, float* __restrict__ feats, float* __restrict__ nrm,
    float* __restrict__ sq) {
  __shared__ float tile[CHN][33];
  __shared__ float part[8][32];
  __shared__ float sinv[32];
  int b = blockIdx.y, n0 = blockIdx.x * 32;
  int tid = threadIdx.x;
  for (int i = tid; i < CHN * 32; i += 256) {
    int c = i >> 5, nn = i & 31;
    float m = stat[(b * CHN + c) * 2];
    float r = stat[(b * CHN + c) * 2 + 1];
    tile[c][nn] = (h[((size_t)(b * CHN + c)) * NP + n0 + nn] - m) * r;
  }
  __syncthreads();
  int nn = tid & 31, sub = tid >> 5;
  float ss = 0.f;
#pragma unroll
  for (int j = 0; j < 12; ++j) { float f = tile[sub * 12 + j][nn]; ss = fmaf(f, f, ss); }
  part[sub][nn] = ss;
  __syncthreads();
  if (tid < 32) {
    float S = 0.f;
#pragma unroll
    for (int w = 0; w < 8; ++w) S += part[w][tid];
    float norm = sqrtf(S);
    sinv[tid] = 1.f / fmaxf(norm, 1e-12f);
  }
  __syncthreads();
  float inv = sinv[nn];
  float ss2 = 0.f;
#pragma unroll
  for (int j = 0; j < 12; ++j) { float f = tile[sub * 12 + j][nn] * inv; ss2 = fmaf(f, f, ss2); }
  part[sub][nn] = ss2;
  __syncthreads();
  if (tid < 32) {
    float S = 0.f;
#pragma unroll
    for (int w = 0; w < 8; ++w) S += part[w][tid];
    sq[(size_t)b * NP + n0 + tid] = S;
  }
  for (int i = tid; i < 32 * CHN; i += 256) {
    int nn2 = i / CHN, c = i - nn2 * CHN;
    float f = tile[c][nn2];
    size_t o = ((size_t)b * NP + n0 + nn2) * CHN + c;
    feats[o] = f;
    nrm[o] = f * sinv[nn2];
  }
}

// ---------- K3b: build MFMA operand streams, 3-way bf16 split (x = h+m+l, exact residuals).
// A (m-side rows): nrm; B (n-side cols): -2*nrm.
// Fragment layout (16x16x32 bf16): lane l -> row/col = l&15, k = (l>>4)*8 + j.
__global__ __launch_bounds__(256) void k3b_prep(const float* __restrict__ nrm,
    ushort* __restrict__ ast, ushort* __restrict__ bst) {
  int b = blockIdx.y, t = blockIdx.x;
  int tid = threadIdx.x;
  const float* nb = nrm + (size_t)b * NP * CHN;
  ushort* ao = ast + (((size_t)b * NT + t) * NFRAG) * 512;
  for (int e = tid; e < NFRAG * 512; e += 256) {
    int f = e >> 9, l = (e >> 3) & 63, j = e & 7;
    int part = f / 3, sl = f - part * 3;
    int c = sl * 32 + (l >> 4) * 8 + j;
    int m = t * 16 + (l & 15);
    float xv = nb[(size_t)m * CHN + c];
    ushort hh = f2bf(xv);
    float rm = xv - bf2f(hh);          // exact
    ushort md = f2bf(rm);
    ushort v = (part == 0) ? hh : (part == 1) ? md : f2bf(rm - bf2f(md));
    ao[e] = v;
  }
  ushort* bo = bst + (((size_t)b * NT + t) * NFRAG) * 512;
  for (int e = tid; e < NFRAG * 512; e += 256) {
    int f = e >> 9, l = (e >> 3) & 63, j = e & 7;
    int part = f / 3, sl = f - part * 3;
    int c = sl * 32 + (l >> 4) * 8 + j;
    int n = t * 16 + (l & 15);
    float y = -2.f * nb[(size_t)n * CHN + c];
    ushort hh = f2bf(y);
    float rm = y - bf2f(hh);
    ushort md = f2bf(rm);
    ushort v = (part == 0) ? hh : (part == 1) ? md : f2bf(rm - bf2f(md));
    bo[e] = v;
  }
}

// ---------- K4: MFMA pairwise key sq_m - 2*dot (18 MFMAs: hh,hm,mh,mm,hl,lh over 3 K-slices)
// + exact fp32 sq_m from global float4 broadcast; per-lane top-9 insert.
// NOTE (round-4 bug): every mfma MUST have C-in == D-out (3rd arg same as dest).
__global__ __launch_bounds__(256, 2) void k4_mfma(
    const ushort* __restrict__ ast, const ushort* __restrict__ bst,
    const float* __restrict__ sq, float* __restrict__ pd, int* __restrict__ pi) {
  int b = blockIdx.z, chunk = blockIdx.y, ng = blockIdx.x;
  int wave = threadIdx.x >> 6, lane = threadIdx.x & 63;
  int tn = ng * 4 + wave;
  const bf16x8* bp = (const bf16x8*)(bst + (((size_t)b * NT + tn) * NFRAG) * 512);
  bf16x8 bh0 = bp[0 * 64 + lane], bh1 = bp[1 * 64 + lane], bh2 = bp[2 * 64 + lane];
  bf16x8 bm0 = bp[3 * 64 + lane], bm1 = bp[4 * 64 + lane], bm2 = bp[5 * 64 + lane];
  bf16x8 bl0 = bp[6 * 64 + lane], bl1 = bp[7 * 64 + lane], bl2 = bp[8 * 64 + lane];
  const float* sqb = sq + (size_t)b * NP;

  __shared__ ushort lds_a[2 * NFRAG * 512];   // 18,432 B double-buffered A tile
  const ushort* astb = ast + ((size_t)b * NT) * (NFRAG * 512);
  int t0 = chunk * TPC;

  // stage tile tg into buffer s: 9 x 1KB segments; wave w does segs {w, w+4}, wave0 also 8
#define STAGE(tg, s) do { \
    const ushort* _src = astb + (size_t)(tg) * (NFRAG * 512); \
    ushort* _dst = lds_a + (s) * (NFRAG * 512); \
    gl2lds16(_src + wave * 512 + lane * 8, _dst + wave * 512); \
    gl2lds16(_src + (wave + 4) * 512 + lane * 8, _dst + (wave + 4) * 512); \
    if (wave == 0) gl2lds16(_src + 8 * 512 + lane * 8, _dst + 8 * 512); \
  } while (0)

  STAGE(t0, 0);
  __syncthreads();

  float tv[KNN]; int ti[KNN];
#pragma unroll
  for (int i = 0; i < KNN; ++i) { tv[i] = FLT_MAX; ti[i] = 0x7fffffff; }

  for (int tl = 0; tl < TPC; ++tl) {
    int cur = tl & 1;
    if (tl + 1 < TPC) STAGE(t0 + tl + 1, cur ^ 1);
    int mbase = (t0 + tl) * 16 + ((lane >> 4) << 2);
    float4 sqv = *(const float4*)(sqb + mbase);   // broadcast within 16-lane group
    const bf16x8* ap = (const bf16x8*)(lds_a + (size_t)cur * (NFRAG * 512));
    bf16x8 ah0 = ap[0 * 64 + lane], ah1 = ap[1 * 64 + lane], ah2 = ap[2 * 64 + lane];
    bf16x8 am0 = ap[3 * 64 + lane], am1 = ap[4 * 64 + lane], am2 = ap[5 * 64 + lane];
    bf16x8 al0 = ap[6 * 64 + lane], al1 = ap[7 * 64 + lane], al2 = ap[8 * 64 + lane];
    // acc0: hh only (large terms); acc1: hm+mh+mm; acc2: hl+lh (tiny terms)
    f32x4 acc0 = {0.f, 0.f, 0.f, 0.f}, acc1 = {0.f, 0.f, 0.f, 0.f}, acc2 = {0.f, 0.f, 0.f, 0.f};
    acc0 = __builtin_amdgcn_mfma_f32_16x16x32_bf16(ah0, bh0, acc0, 0, 0, 0);
    acc1 = __builtin_amdgcn_mfma_f32_16x16x32_bf16(am0, bh0, acc1, 0, 0, 0);
    acc2 = __builtin_amdgcn_mfma_f32_16x16x32_bf16(al0, bh0, acc2, 0, 0, 0);
    acc1 = __builtin_amdgcn_mfma_f32_16x16x32_bf16(ah0, bm0, acc1, 0, 0, 0);
    acc2 = __builtin_amdgcn_mfma_f32_16x16x32_bf16(ah0, bl0, acc2, 0, 0, 0);
    acc1 = __builtin_amdgcn_mfma_f32_16x16x32_bf16(am0, bm0, acc1, 0, 0, 0);
    acc0 = __builtin_amdgcn_mfma_f32_16x16x32_bf16(ah1, bh1, acc0, 0, 0, 0);
    acc1 = __builtin_amdgcn_mfma_f32_16x16x32_bf16(am1, bh1, acc1, 0, 0, 0);
    acc2 = __builtin_amdgcn_mfma_f32_16x16x32_bf16(al1, bh1, acc2, 0, 0, 0);
    acc1 = __builtin_amdgcn_mfma_f32_16x16x32_bf16(ah1, bm1, acc1, 0, 0, 0);
    acc2 = __builtin_amdgcn_mfma_f32_16x16x32_bf16(ah1, bl1, acc2, 0, 0, 0);
    acc1 = __builtin_amdgcn_mfma_f32_16x16x32_bf16(am1, bm1, acc1, 0, 0, 0);
    acc0 = __builtin_amdgcn_mfma_f32_16x16x32_bf16(ah2, bh2, acc0, 0, 0, 0);
    acc1 = __builtin_amdgcn_mfma_f32_16x16x32_bf16(am2, bh2, acc1, 0, 0, 0);
    acc2 = __builtin_amdgcn_mfma_f32_16x16x32_bf16(al2, bh2, acc2, 0, 0, 0);
    acc1 = __builtin_amdgcn_mfma_f32_16x16x32_bf16(ah2, bm2, acc1, 0, 0, 0);
    acc2 = __builtin_amdgcn_mfma_f32_16x16x32_bf16(ah2, bl2, acc2, 0, 0, 0);
    acc1 = __builtin_amdgcn_mfma_f32_16x16x32_bf16(am2, bm2, acc1, 0, 0, 0);  // FIXED: was acc2->acc1
#pragma unroll
    for (int r = 0; r < 4; ++r) {
      float d = ((acc1[r] + acc2[r]) + acc0[r]) + sqv[r];  // small->large summation
      int m = mbase + r;
      if (d < tv[KNN - 1]) {     // strict <: equal keys keep earlier index
        tv[8] = d; ti[8] = m;
#pragma unroll
        for (int j = 8; j > 0; --j) {
          bool swp = tv[j] < tv[j - 1];
          float fa = swp ? tv[j] : tv[j - 1];
          float fb = swp ? tv[j - 1] : tv[j];
          int ia = swp ? ti[j] : ti[j - 1];
          int ib = swp ? ti[j - 1] : ti[j];
          tv[j - 1] = fa; tv[j] = fb; ti[j - 1] = ia; ti[j] = ib;
        }
      }
    }
    __syncthreads();
  }
#undef STAGE
  int g = lane >> 4;
  int n = tn * 16 + (lane & 15);
  size_t base = (((size_t)b * NLIST + (chunk * 4 + g)) * NP + n) * (size_t)KNN;
#pragma unroll
  for (int i = 0; i < KNN; ++i) { pd[base + i] = tv[i]; pi[base + i] = ti[i]; }
}

// ---------- K4b: merge 16 sorted top-9 lists per query (LDS-resident selection)
__global__ __launch_bounds__(64) void k4b_merge(const float* __restrict__ pd,
    const int* __restrict__ pi, int* __restrict__ nidx) {
  __shared__ float  sd[64][NLIST * KNN + 1];   // 37.1 KB
  __shared__ ushort si[64][NLIST * KNN + 1];   // 18.6 KB
  int tid = threadIdx.x;
  int q = blockIdx.x * 64 + tid;
  int b = q / NP, n = q - b * NP;
  for (int ch = 0; ch < NLIST; ++ch) {
    size_t base = (((size_t)b * NLIST + ch) * NP + n) * (size_t)KNN;
#pragma unroll
    for (int k = 0; k < KNN; ++k) {
      sd[tid][ch * KNN + k] = pd[base + k];
      si[tid][ch * KNN + k] = (ushort)pi[base + k];
    }
  }
  float dl = -FLT_MAX; int il = -1;
  int* op = nidx + (size_t)q * KNN;
  for (int k = 0; k < KNN; ++k) {
    float bd = FLT_MAX; int bi = 0x7fffffff;
    for (int j = 0; j < NLIST * KNN; ++j) {
      float d = sd[tid][j]; int i = (int)si[tid][j];
      bool gt = (d > dl) || ((d == dl) && (i > il));
      bool lt = (d < bd) || ((d == bd) && (i < bi));
      if (gt && lt) { bd = d; bi = i; }
    }
    op[k] = bi; dl = bd; il = bi;
  }
}

// ---------- K5: a = (W1-W2)·f + gb ; u = W2·f
__global__ __launch_bounds__(256) void k5_au(const float* __restrict__ feats,
    const float* __restrict__ gw, const float* __restrict__ gb,
    float* __restrict__ a, float* __restrict__ u) {
  __shared__ float sf[32][97];
  __shared__ float swc[64 * C2];
  int b = blockIdx.y, n0 = blockIdx.x * 32;
  int tid = threadIdx.x;
  for (int i = tid; i < 32 * CHN; i += 256) {
    int nn = i / CHN, c = i - nn * CHN;
    sf[nn][c] = feats[((size_t)b * NP + n0 + nn) * CHN + c];
  }
  int nn = tid & 31, sub = tid >> 5;
  for (int oc = 0; oc < 3; ++oc) {
    __syncthreads();
    for (int i = tid; i < 64 * C2; i += 256) swc[i] = gw[(size_t)(oc * 64) * C2 + i];
    __syncthreads();
    float accA[8], accU[8];
#pragma unroll
    for (int j = 0; j < 8; ++j) { accA[j] = 0.f; accU[j] = 0.f; }
    for (int c = 0; c < CHN; ++c) {
      float f = sf[nn][c];
#pragma unroll
      for (int j = 0; j < 8; ++j) {
        float w1 = swc[(sub * 8 + j) * C2 + c];
        float wv2 = swc[(sub * 8 + j) * C2 + 96 + c];
        accA[j] = fmaf(w1 - wv2, f, accA[j]);
        accU[j] = fmaf(wv2, f, accU[j]);
      }
    }
    size_t row = ((size_t)b * NP + n0 + nn) * C2;
#pragma unroll
    for (int j = 0; j < 8; ++j) {
      int o = oc * 64 + sub * 8 + j;
      a[row + o] = accA[j] + gb[o];
      u[row + o] = accU[j];
    }
  }
}

// ---------- K6: agg = relu(a + max_k u[idx_k]); ol = fc2_w·agg + fc2_b
__global__ __launch_bounds__(256) void k6_edge(const float* __restrict__ a,
    const float* __restrict__ u, const int* __restrict__ nidx,
    const float* __restrict__ w2, const float* __restrict__ b2, float* __restrict__ ol) {
  __shared__ float sagg[32][193];
  int b = blockIdx.y, n0 = blockIdx.x * 32;
  int tid = threadIdx.x;
  int wv = tid >> 6, ln = tid & 63;
  for (int p = 0; p < 8; ++p) {
    int nn = wv * 8 + p;
    size_t row = (size_t)b * NP + n0 + nn;
    const int* ip = nidx + row * KNN;
    int idx[KNN];
#pragma unroll
    for (int k = 0; k < KNN; ++k) idx[k] = ip[k];
#pragma unroll
    for (int oo = 0; oo < 3; ++oo) {
      int o = oo * 64 + ln;
      float umax = -FLT_MAX;
#pragma unroll
      for (int k = 0; k < KNN; ++k)
        umax = fmaxf(umax, u[((size_t)b * NP + idx[k]) * C2 + o]);
      float av = a[row * C2 + o];
      sagg[nn][o] = fmaxf(av + umax, 0.f);
    }
  }
  __syncthreads();
  int nn = tid & 31, sub = tid >> 5;
  for (int j = 0; j < 12; ++j) {
    int o2 = sub + 8 * j;
    float acc = b2[o2];
    for (int o = 0; o < C2; ++o) acc = fmaf(w2[o2 * C2 + o], sagg[nn][o], acc);
    ol[((size_t)b * CHN + o2) * NP + n0 + nn] = acc;
  }
}

// ---------- K8: out = (ol - mean)*rstd + shortcut
__global__ __launch_bounds__(256) void k8_final(const float* __restrict__ ol,
    const float* __restrict__ stat, const float* __restrict__ x, float* __restrict__ out) {
  int i = blockIdx.x * 256 + threadIdx.x;
  int bo = i / NP;
  float m = stat[bo * 2], r = stat[bo * 2 + 1];
  out[i] = fmaf(ol[i] - m, r, x[i]);
}

extern "C" void kernel_launch(void* const* d_in, const int* in_sizes, int n_in,
                              void* d_out, int out_size, void* d_ws, size_t ws_size,
                              hipStream_t stream) {
  const float* x   = (const float*)d_in[0];
  const float* f1w = (const float*)d_in[1];
  const float* f1b = (const float*)d_in[2];
  const float* gw  = (const float*)d_in[3];
  const float* gb  = (const float*)d_in[4];
  const float* f2w = (const float*)d_in[5];
  const float* f2b = (const float*)d_in[6];
  float* out = (float*)d_out;
  char* ws = (char*)d_ws;

  // lifetime-aliased arena (78.1 MB total):
  // R0 [0..28.9M):       h(k1-k3) | pd@0,pi@14.45M (k4-k4b) | a(k5-k6)
  // R1 [28.9..57.8M):    ast@28.9M,bst@43.35M (k3b-k4) | u@28.9M (k5-k6)
  // R2 [57.8..67.44M):   nrm (k3-k3b) | ol (k6-k8)
  // R3 [67.44..77.07M):  feats (k3-k5)
  // R4 [77.07M..):       sq, st1, st2, ni
  constexpr size_t SZ_MAT = (size_t)BQ * CHN * NP * 4;           // 9,633,792
  constexpr size_t SZ_STR = (size_t)BQ * NT * NFRAG * 512 * 2;   // 14,450,688
  constexpr size_t SZ_PL  = (size_t)BQ * NLIST * NP * KNN * 4;   // 14,450,688
  constexpr size_t OFF_H   = 0;
  constexpr size_t OFF_PD  = 0;
  constexpr size_t OFF_PI  = OFF_PD + SZ_PL;
  constexpr size_t OFF_A   = 0;
  constexpr size_t OFF_AST = 2 * SZ_PL;                          // 28,901,376
  constexpr size_t OFF_BST = OFF_AST + SZ_STR;
  constexpr size_t OFF_U   = OFF_AST;
  constexpr size_t OFF_NRM = OFF_AST + 2 * SZ_STR;               // 57,802,752
  constexpr size_t OFF_OL  = OFF_NRM;
  constexpr size_t OFF_FE  = OFF_NRM + SZ_MAT;                   // 67,436,544
  constexpr size_t OFF_SQ  = OFF_FE + SZ_MAT;                    // 77,070,336
  constexpr size_t OFF_ST1 = OFF_SQ + (size_t)BQ * NP * 4;
  constexpr size_t OFF_ST2 = OFF_ST1 + (size_t)BQ * CHN * 2 * 4;
  constexpr size_t OFF_NI  = OFF_ST2 + (size_t)BQ * CHN * 2 * 4; // ends 78,086,144

  float* h   = (float*)(ws + OFF_H);
  float* fe  = (float*)(ws + OFF_FE);
  float* nrm = (float*)(ws + OFF_NRM);
  float* sq  = (float*)(ws + OFF_SQ);
  float* st1 = (float*)(ws + OFF_ST1);
  float* st2 = (float*)(ws + OFF_ST2);
  int*   ni  = (int*)(ws + OFF_NI);
  ushort* ast = (ushort*)(ws + OFF_AST);
  ushort* bst = (ushort*)(ws + OFF_BST);
  float* pd  = (float*)(ws + OFF_PD);
  int*   pi  = (int*)(ws + OFF_PI);
  float* aA  = (float*)(ws + OFF_A);
  float* uU  = (float*)(ws + OFF_U);
  float* ol  = (float*)(ws + OFF_OL);

  k1_conv1<<<dim3(NP / 64, BQ), 256, 0, stream>>>(x, f1w, f1b, h);
  k2_stats<<<dim3(BQ * CHN), 256, 0, stream>>>(h, st1);
  k3_norm<<<dim3(NP / 32, BQ), 256, 0, stream>>>(h, st1, fe, nrm, sq);
  k3b_prep<<<dim3(NT, BQ), 256, 0, stream>>>(nrm, ast, bst);
  k4_mfma<<<dim3(NT / 4, MCH, BQ), 256, 0, stream>>>(ast, bst, sq, pd, pi);
  k4b_merge<<<dim3(BQ * NP / 64), 64, 0, stream>>>(pd, pi, ni);
  k5_au<<<dim3(NP / 32, BQ), 256, 0, stream>>>(fe, gw, gb, aA, uU);
  k6_edge<<<dim3(NP / 32, BQ), 256, 0, stream>>>(aA, uU, ni, f2w, f2b, ol);
  k2_stats<<<dim3(BQ * CHN), 256, 0, stream>>>(ol, st2);
  k8_final<<<dim3(BQ * CHN * NP / 256), 256, 0, stream>>>(ol, st2, x, out);
}